// Round 1
// baseline (168.386 us; speedup 1.0000x reference)
//
#include <hip/hip_runtime.h>

// Problem: B=256, L=8192, C=8. real: one-hot f32 [B,L,C]; pred: uniform f32 [B,L,C].
// Output: scalar f32 combined loss.
#define NPOS (256 * 8192)   // B*L = 2097152 positions
// C = 8 floats = 32 bytes per position per tensor -> 2x float4 loads each.

__global__ __launch_bounds__(256) void ss_acc_loss_main(
    const float* __restrict__ real,
    const float* __restrict__ pred,
    unsigned int* __restrict__ counts)  // counts[0]=argmax matches, counts[1]=exact matches
{
    int tid    = blockIdx.x * blockDim.x + threadIdx.x;
    int stride = gridDim.x * blockDim.x;

    unsigned int c_arg = 0, c_exact = 0;

    for (int i = tid; i < NPOS; i += stride) {
        const float4* rp = reinterpret_cast<const float4*>(real + (size_t)i * 8);
        const float4* pp = reinterpret_cast<const float4*>(pred + (size_t)i * 8);
        float4 r0 = rp[0], r1 = rp[1];
        float4 p0 = pp[0], p1 = pp[1];

        float r[8] = {r0.x, r0.y, r0.z, r0.w, r1.x, r1.y, r1.z, r1.w};
        float p[8] = {p0.x, p0.y, p0.z, p0.w, p1.x, p1.y, p1.z, p1.w};

        // argmax with first-occurrence tie-break (strict >)
        int   ta = 0;   float tm = r[0];
        int   pa = 0;   float pm = p[0];
        bool  exact = true;
        #pragma unroll
        for (int k = 0; k < 8; ++k) {
            if (r[k] > tm) { tm = r[k]; ta = k; }
            if (p[k] > pm) { pm = p[k]; pa = k; }
            float pl = (p[k] > 0.5f) ? 1.0f : 0.0f;
            exact = exact && (r[k] == pl);  // real entries are exactly 0.0f / 1.0f
        }
        c_arg   += (pa == ta) ? 1u : 0u;
        c_exact += exact ? 1u : 0u;
    }

    // wave64 butterfly reduce
    #pragma unroll
    for (int off = 32; off > 0; off >>= 1) {
        c_arg   += __shfl_down(c_arg,   off, 64);
        c_exact += __shfl_down(c_exact, off, 64);
    }

    __shared__ unsigned int s1[4], s2[4];  // 256 threads = 4 waves
    int wave = threadIdx.x >> 6;
    int lane = threadIdx.x & 63;
    if (lane == 0) { s1[wave] = c_arg; s2[wave] = c_exact; }
    __syncthreads();

    if (threadIdx.x == 0) {
        unsigned int t1 = s1[0] + s1[1] + s1[2] + s1[3];
        unsigned int t2 = s2[0] + s2[1] + s2[2] + s2[3];
        atomicAdd(&counts[0], t1);   // device-scope by default on CDNA
        atomicAdd(&counts[1], t2);
    }
}

__global__ void ss_acc_loss_finalize(const unsigned int* __restrict__ counts,
                                     float* __restrict__ out)
{
    const float inv_n = 1.0f / (float)NPOS;  // N is 2^21 -> exact
    float acc_max = (float)counts[0] * inv_n;
    float acc_lab = (float)counts[1] * inv_n;
    out[0] = 0.5f * (1.0f - acc_max) + 0.5f * (1.0f - acc_lab);
}

extern "C" void kernel_launch(void* const* d_in, const int* in_sizes, int n_in,
                              void* d_out, int out_size, void* d_ws, size_t ws_size,
                              hipStream_t stream) {
    const float* real = (const float*)d_in[0];
    const float* pred = (const float*)d_in[1];
    unsigned int* counts = (unsigned int*)d_ws;
    float* out = (float*)d_out;

    // d_ws is poisoned 0xAA before every launch -> zero the two counters.
    hipMemsetAsync(counts, 0, 2 * sizeof(unsigned int), stream);

    const int block = 256;
    const int grid  = 2048;  // ~8 blocks/CU worth of waves; grid-stride covers 2M positions
    ss_acc_loss_main<<<grid, block, 0, stream>>>(real, pred, counts);
    ss_acc_loss_finalize<<<1, 1, 0, stream>>>(counts, out);
}